// Round 1
// baseline (280.519 us; speedup 1.0000x reference)
//
#include <hip/hip_runtime.h>
#include <math.h>

#define S_LEN 2048
#define E_DIM 512
#define NE (S_LEN * E_DIM)
#define H_NUM 8
#define WH 32
#define NOFF 65
#define PROW (H_NUM * NOFF) /* 520 */

// ---------------------------------------------------------------------------
// Tiled fp32 GEMM: C = (A @ W + bias) * scale [+ resid]
// A: M x 512 (M=2048), W: 512 x 512. Tile 64x64, 256 threads, 4x4 per thread.
// ---------------------------------------------------------------------------
__device__ __forceinline__ void gemm_body(
    const float* __restrict__ A, const float* __restrict__ W,
    const float* __restrict__ bias, const float* __restrict__ resid,
    float* __restrict__ C, float scale)
{
    __shared__ float As[64][17];   // [m][k], pad 17 -> 2-way max on strided reads
    __shared__ float Bs[16][64];   // [k][n]
    const int tid = threadIdx.x;
    const int tx = tid & 15, ty = tid >> 4;
    const int m0 = blockIdx.y * 64, n0 = blockIdx.x * 64;
    float acc[4][4] = {};

    for (int kk = 0; kk < E_DIM; kk += 16) {
#pragma unroll
        for (int l = 0; l < 4; ++l) {
            int e = tid + l * 256;
            As[e >> 4][e & 15] = A[(size_t)(m0 + (e >> 4)) * E_DIM + kk + (e & 15)];
            Bs[e >> 6][e & 63] = W[(size_t)(kk + (e >> 6)) * E_DIM + n0 + (e & 63)];
        }
        __syncthreads();
#pragma unroll
        for (int k = 0; k < 16; ++k) {
            float a[4], b[4];
#pragma unroll
            for (int i = 0; i < 4; ++i) a[i] = As[ty * 4 + i][k];
#pragma unroll
            for (int j = 0; j < 4; ++j) b[j] = Bs[k][tx * 4 + j];
#pragma unroll
            for (int i = 0; i < 4; ++i)
#pragma unroll
                for (int j = 0; j < 4; ++j) acc[i][j] += a[i] * b[j];
        }
        __syncthreads();
    }

#pragma unroll
    for (int i = 0; i < 4; ++i) {
        int m = m0 + ty * 4 + i;
#pragma unroll
        for (int j = 0; j < 4; ++j) {
            int n = n0 + tx * 4 + j;
            float r = (acc[i][j] + bias[n]) * scale;
            if (resid) r += resid[(size_t)m * E_DIM + n];
            C[(size_t)m * E_DIM + n] = r;
        }
    }
}

__global__ __launch_bounds__(256)
void qkv_gemm(const float* __restrict__ x,
              const float* __restrict__ Wq, const float* __restrict__ bq,
              const float* __restrict__ Wk, const float* __restrict__ bk,
              const float* __restrict__ Wv, const float* __restrict__ bv,
              float* __restrict__ q, float* __restrict__ k, float* __restrict__ v)
{
    const float* W; const float* b; float* o; float sc;
    if (blockIdx.z == 0)      { W = Wq; b = bq; o = q; sc = 0.125f; } // 1/sqrt(D), D=64
    else if (blockIdx.z == 1) { W = Wk; b = bk; o = k; sc = 1.0f; }
    else                      { W = Wv; b = bv; o = v; sc = 1.0f; }
    gemm_body(x, W, b, nullptr, o, sc);
}

__global__ __launch_bounds__(256)
void o_gemm(const float* __restrict__ hin, const float* __restrict__ Wo,
            const float* __restrict__ bo, const float* __restrict__ x,
            float* __restrict__ y)
{
    gemm_body(hin, Wo, bo, x, y, 1.0f);
}

// ---------------------------------------------------------------------------
// Scores + edge-softmax -> P[i][h][off], off in [0,65), src j = i-32+off.
// Invalid (out-of-range) edges produce exactly P = 0.
// ---------------------------------------------------------------------------
__global__ __launch_bounds__(256)
void scores_kernel(const float* __restrict__ q, const float* __restrict__ k,
                   const float* __restrict__ amask, float* __restrict__ P)
{
    const int i = blockIdx.x;
    const int tid = threadIdx.x;
    __shared__ float qs[E_DIM];
    __shared__ float sc[PROW];
    __shared__ float smax[H_NUM], sden[H_NUM];

    for (int e = tid; e < E_DIM; e += 256) qs[e] = q[(size_t)i * E_DIM + e];
    __syncthreads();

    for (int p = tid; p < PROW; p += 256) {
        int h = p / NOFF, off = p - h * NOFF;
        int j = i - WH + off;
        float s;
        if (j < 0 || j >= S_LEN) {
            s = -INFINITY;               // edge does not exist
        } else {
            const float4* k4 = (const float4*)(k + (size_t)j * E_DIM + h * 64);
            const float4* q4 = (const float4*)(qs + h * 64);
            float acc = 0.f;
#pragma unroll
            for (int t = 0; t < 16; ++t) {
                float4 a = q4[t], bb = k4[t];
                acc += a.x * bb.x + a.y * bb.y + a.z * bb.z + a.w * bb.w;
            }
            s = (amask[j] >= 0.f) ? acc : -1e9f;   // mask on src node
        }
        sc[p] = s;
    }
    __syncthreads();

    if (tid < H_NUM) {
        float mx = -INFINITY;
        for (int o = 0; o < NOFF; ++o) mx = fmaxf(mx, sc[tid * NOFF + o]);
        float dn = 0.f;
        for (int o = 0; o < NOFF; ++o) dn += expf(sc[tid * NOFF + o] - mx);
        smax[tid] = mx; sden[tid] = dn;
    }
    __syncthreads();

    for (int p = tid; p < PROW; p += 256) {
        int h = p / NOFF;
        float pv = expf(sc[p] - smax[h]) / sden[h];  // expf(-inf - finite) = 0
        P[(size_t)i * PROW + p] = pv;
    }
}

// ---------------------------------------------------------------------------
// One diffusion step: hout[i,c] = 0.9 * sum_off P[i,h(c),off] * hin[j,c] + 0.1*v[i,c]
// 512 threads = one per column c; P row staged in LDS (broadcast reads).
// ---------------------------------------------------------------------------
__global__ __launch_bounds__(512)
void diffuse(const float* __restrict__ hin, const float* __restrict__ v,
             const float* __restrict__ P, float* __restrict__ hout)
{
    const int i = blockIdx.x;
    const int c = threadIdx.x;
    __shared__ float pr[PROW];
    for (int e = c; e < PROW; e += 512) pr[e] = P[(size_t)i * PROW + e];
    __syncthreads();

    const float* ph = pr + (c >> 6) * NOFF;
    float acc = 0.f;
    const int j0 = i - WH;
    for (int off = 0; off < NOFF; ++off) {
        int j = j0 + off;
        int jc = min(max(j, 0), S_LEN - 1);     // P==0 for invalid, clamp is safe
        acc += ph[off] * hin[(size_t)jc * E_DIM + c];
    }
    hout[(size_t)i * E_DIM + c] = 0.9f * acc + 0.1f * v[(size_t)i * E_DIM + c];
}

// ---------------------------------------------------------------------------
// LayerNorm over E=512 per node. 256 threads x 2 elements.
// ---------------------------------------------------------------------------
__global__ __launch_bounds__(256)
void layernorm(const float* __restrict__ y, const float* __restrict__ g,
               const float* __restrict__ b, float* __restrict__ out)
{
    const int i = blockIdx.x;
    const int tid = threadIdx.x;
    float x0 = y[(size_t)i * E_DIM + tid];
    float x1 = y[(size_t)i * E_DIM + 256 + tid];
    float s = x0 + x1, s2 = x0 * x0 + x1 * x1;
#pragma unroll
    for (int o = 1; o < 64; o <<= 1) {
        s  += __shfl_xor(s, o, 64);
        s2 += __shfl_xor(s2, o, 64);
    }
    __shared__ float ssum[4], ssq[4];
    int wv = tid >> 6, ln = tid & 63;
    if (ln == 0) { ssum[wv] = s; ssq[wv] = s2; }
    __syncthreads();
    float tot  = ssum[0] + ssum[1] + ssum[2] + ssum[3];
    float tot2 = ssq[0] + ssq[1] + ssq[2] + ssq[3];
    float mu = tot * (1.f / 512.f);
    float var = tot2 * (1.f / 512.f) - mu * mu;
    float rs = rsqrtf(var + 1e-12f);
    out[(size_t)i * E_DIM + tid]       = (x0 - mu) * rs * g[tid]       + b[tid];
    out[(size_t)i * E_DIM + 256 + tid] = (x1 - mu) * rs * g[tid + 256] + b[tid + 256];
}

// ---------------------------------------------------------------------------
extern "C" void kernel_launch(void* const* d_in, const int* in_sizes, int n_in,
                              void* d_out, int out_size, void* d_ws, size_t ws_size,
                              hipStream_t stream)
{
    const float* x     = (const float*)d_in[0];
    const float* amask = (const float*)d_in[1];
    // d_in[2]/d_in[3]: edge_src/edge_dst — deterministic ±32 band, recomputed on the fly
    const float* Wq = (const float*)d_in[4];
    const float* bq = (const float*)d_in[5];
    const float* Wk = (const float*)d_in[6];
    const float* bk = (const float*)d_in[7];
    const float* Wv = (const float*)d_in[8];
    const float* bv = (const float*)d_in[9];
    const float* Wo = (const float*)d_in[10];
    const float* bo = (const float*)d_in[11];
    const float* lng = (const float*)d_in[12];
    const float* lnb = (const float*)d_in[13];
    float* out = (float*)d_out;

    float* ws = (float*)d_ws;
    float* q  = ws;                 // reused as y after scores
    float* k  = ws + (size_t)NE;    // reused as hB after scores
    float* v  = ws + (size_t)2 * NE;
    float* hA = ws + (size_t)3 * NE;
    float* P  = ws + (size_t)4 * NE;
    float* hB = k;
    float* y  = q;

    dim3 gq(E_DIM / 64, S_LEN / 64, 3);
    qkv_gemm<<<gq, 256, 0, stream>>>(x, Wq, bq, Wk, bk, Wv, bv, q, k, v);

    scores_kernel<<<S_LEN, 256, 0, stream>>>(q, k, amask, P);

    diffuse<<<S_LEN, 512, 0, stream>>>(v,  v, P, hA);
    diffuse<<<S_LEN, 512, 0, stream>>>(hA, v, P, hB);
    diffuse<<<S_LEN, 512, 0, stream>>>(hB, v, P, hA);
    diffuse<<<S_LEN, 512, 0, stream>>>(hA, v, P, hB);
    diffuse<<<S_LEN, 512, 0, stream>>>(hB, v, P, hA);

    o_gemm<<<dim3(E_DIM / 64, S_LEN / 64), 256, 0, stream>>>(hA, Wo, bo, x, y);

    layernorm<<<S_LEN, 256, 0, stream>>>(y, lng, lnb, out);
}

// Round 2
// 233.633 us; speedup vs baseline: 1.2007x; 1.2007x over previous
//
#include <hip/hip_runtime.h>
#include <math.h>

#define S_LEN 2048
#define E_DIM 512
#define NE (S_LEN * E_DIM)
#define H_NUM 8
#define WH 32
#define NOFF 65
#define PROW (H_NUM * NOFF) /* 520 */
#define PN (S_LEN * PROW)

typedef float f32x4 __attribute__((ext_vector_type(4)));
typedef short short8 __attribute__((ext_vector_type(8)));

__device__ __forceinline__ unsigned short f2bf(float f) {
    union { float f; unsigned u; } cv; cv.f = f;
    unsigned u = cv.u;
    u += 0x7fffu + ((u >> 16) & 1u);   // RNE
    return (unsigned short)(u >> 16);
}

// ---------------------------------------------------------------------------
// prep: z<4 -> transpose+cast weight z to bf16 [n][k]; z==4 -> cast x to bf16.
// ---------------------------------------------------------------------------
__global__ __launch_bounds__(256)
void prep(const float* __restrict__ x,
          const float* __restrict__ Wq, const float* __restrict__ Wk,
          const float* __restrict__ Wv, const float* __restrict__ Wo,
          unsigned short* __restrict__ xb,
          unsigned short* __restrict__ WqT, unsigned short* __restrict__ WkT,
          unsigned short* __restrict__ WvT, unsigned short* __restrict__ WoT)
{
    const int tid = threadIdx.x;
    const int z = blockIdx.z;
    if (z < 4) {
        const float* W = (z == 0) ? Wq : (z == 1) ? Wk : (z == 2) ? Wv : Wo;
        unsigned short* Wt = (z == 0) ? WqT : (z == 1) ? WkT : (z == 2) ? WvT : WoT;
        __shared__ float tile[64][65];
        const int n0 = blockIdx.x * 64, k0 = blockIdx.y * 64;
        const int r = tid >> 2;
#pragma unroll
        for (int s = 0; s < 4; ++s) {
            int c4 = (tid & 3) + 4 * s;
            float4 vv = ((const float4*)(W + (size_t)(k0 + r) * E_DIM + n0))[c4];
            tile[r][c4 * 4 + 0] = vv.x; tile[r][c4 * 4 + 1] = vv.y;
            tile[r][c4 * 4 + 2] = vv.z; tile[r][c4 * 4 + 3] = vv.w;
        }
        __syncthreads();
        // Wt[n0+r][k0+c] = tile[c][r]
#pragma unroll
        for (int s = 0; s < 4; ++s) {
            int c4 = (tid & 3) + 4 * s;
            ushort4 o;
            o.x = f2bf(tile[c4 * 4 + 0][r]);
            o.y = f2bf(tile[c4 * 4 + 1][r]);
            o.z = f2bf(tile[c4 * 4 + 2][r]);
            o.w = f2bf(tile[c4 * 4 + 3][r]);
            *(ushort4*)(Wt + (size_t)(n0 + r) * E_DIM + k0 + c4 * 4) = o;
        }
    } else {
        // cast x (NE elems) in 64 chunks of 16384
        const int chunk = blockIdx.y * 8 + blockIdx.x;
        const float4* x4 = (const float4*)x;
        ushort4* xb4 = (ushort4*)xb;
#pragma unroll
        for (int it = 0; it < 16; ++it) {
            int idx = chunk * 4096 + it * 256 + tid;
            float4 vv = x4[idx];
            ushort4 o;
            o.x = f2bf(vv.x); o.y = f2bf(vv.y); o.z = f2bf(vv.z); o.w = f2bf(vv.w);
            xb4[idx] = o;
        }
    }
}

// ---------------------------------------------------------------------------
// bf16 MFMA GEMM: C = (A@W + bias)*scale [+ resid].  A: bf16 [m][k], Wt: bf16
// [n][k].  Tile 64x64, 4 waves each 32x32 (2x2 MFMA 16x16x32), BK=32.
// ---------------------------------------------------------------------------
__device__ __forceinline__ void mfma_gemm(
    const unsigned short* __restrict__ A, const unsigned short* __restrict__ Wt,
    const float* __restrict__ bias, const float* __restrict__ resid,
    float* __restrict__ C, float scale, int m0, int n0)
{
    __shared__ unsigned short As[64 * 40];  // [row][k] pad 40 (2-way bank max)
    __shared__ unsigned short Bs[64 * 40];  // [n][k]
    const int tid = threadIdx.x;
    const int lane = tid & 63, wave = tid >> 6;
    const int quad = lane >> 4, l16 = lane & 15;
    const int wr = (wave >> 1) * 32, wc = (wave & 1) * 32;
    const int srow = tid >> 2, sch = (tid & 3) * 8;

    f32x4 acc00 = {0.f,0.f,0.f,0.f}, acc01 = acc00, acc10 = acc00, acc11 = acc00;

    for (int kk = 0; kk < E_DIM; kk += 32) {
        *(uint4*)(As + srow * 40 + sch) =
            *(const uint4*)(A + (size_t)(m0 + srow) * E_DIM + kk + sch);
        *(uint4*)(Bs + srow * 40 + sch) =
            *(const uint4*)(Wt + (size_t)(n0 + srow) * E_DIM + kk + sch);
        __syncthreads();
        short8 a0 = *(const short8*)(As + (wr + l16) * 40 + quad * 8);
        short8 a1 = *(const short8*)(As + (wr + 16 + l16) * 40 + quad * 8);
        short8 b0 = *(const short8*)(Bs + (wc + l16) * 40 + quad * 8);
        short8 b1 = *(const short8*)(Bs + (wc + 16 + l16) * 40 + quad * 8);
        acc00 = __builtin_amdgcn_mfma_f32_16x16x32_bf16(a0, b0, acc00, 0, 0, 0);
        acc01 = __builtin_amdgcn_mfma_f32_16x16x32_bf16(a0, b1, acc01, 0, 0, 0);
        acc10 = __builtin_amdgcn_mfma_f32_16x16x32_bf16(a1, b0, acc10, 0, 0, 0);
        acc11 = __builtin_amdgcn_mfma_f32_16x16x32_bf16(a1, b1, acc11, 0, 0, 0);
        __syncthreads();
    }

    // C/D layout: col = lane&15, row = quad*4 + reg
#pragma unroll
    for (int mi = 0; mi < 2; ++mi) {
#pragma unroll
        for (int ni = 0; ni < 2; ++ni) {
            f32x4 a = (mi == 0) ? ((ni == 0) ? acc00 : acc01)
                                : ((ni == 0) ? acc10 : acc11);
            int n = n0 + wc + ni * 16 + l16;
            float bval = bias[n];
#pragma unroll
            for (int r = 0; r < 4; ++r) {
                int m = m0 + wr + mi * 16 + quad * 4 + r;
                float vl = (a[r] + bval) * scale;
                if (resid) vl += resid[(size_t)m * E_DIM + n];
                C[(size_t)m * E_DIM + n] = vl;
            }
        }
    }
}

__global__ __launch_bounds__(256)
void qkv_gemm(const unsigned short* __restrict__ xb,
              const unsigned short* __restrict__ WqT, const float* __restrict__ bq,
              const unsigned short* __restrict__ WkT, const float* __restrict__ bk,
              const unsigned short* __restrict__ WvT, const float* __restrict__ bv,
              float* __restrict__ q, float* __restrict__ k, float* __restrict__ v)
{
    const unsigned short* Wt; const float* b; float* o; float sc;
    if (blockIdx.z == 0)      { Wt = WqT; b = bq; o = q; sc = 0.125f; }
    else if (blockIdx.z == 1) { Wt = WkT; b = bk; o = k; sc = 1.0f; }
    else                      { Wt = WvT; b = bv; o = v; sc = 1.0f; }
    mfma_gemm(xb, Wt, b, nullptr, o, sc, blockIdx.y * 64, blockIdx.x * 64);
}

__global__ __launch_bounds__(256)
void o_gemm(const unsigned short* __restrict__ hb, const unsigned short* __restrict__ WoT,
            const float* __restrict__ bo, const float* __restrict__ x,
            float* __restrict__ y)
{
    mfma_gemm(hb, WoT, bo, x, y, 1.0f, blockIdx.y * 64, blockIdx.x * 64);
}

// ---------------------------------------------------------------------------
// scores: block = 64 dst nodes x 1 head. k-tile + masks in LDS, q in regs.
// P[i][h][off] with exact zeros for nonexistent edges.
// ---------------------------------------------------------------------------
__global__ __launch_bounds__(256)
void scores_kernel(const float* __restrict__ q, const float* __restrict__ k,
                   const float* __restrict__ amask, float* __restrict__ P)
{
    const int i0 = blockIdx.x * 64;
    const int h  = blockIdx.y;
    const int tid = threadIdx.x;
    __shared__ float ks[128 * 68];     // rows j = i0-32+lr, 64 cols pad 68
    __shared__ float am[128];
    __shared__ float sc[NOFF * 64];    // [off][dst]
    __shared__ float smx[64], sidn[64];

    for (int e = tid; e < 128 * 16; e += 256) {
        int lr = e >> 4, c4 = e & 15;
        int j = i0 - WH + lr;
        int jc = min(max(j, 0), S_LEN - 1);
        *(float4*)(ks + lr * 68 + c4 * 4) =
            *(const float4*)(k + (size_t)jc * E_DIM + h * 64 + c4 * 4);
    }
    if (tid < 128) {
        int j = i0 - WH + tid;
        am[tid] = (j >= 0 && j < S_LEN) ? amask[j] : -1.0f;
    }

    const int dst = tid >> 2;
    const int oph = tid & 3;
    float4 qreg[16];
    {
        const float4* qrow = (const float4*)(q + (size_t)(i0 + dst) * E_DIM + h * 64);
#pragma unroll
        for (int t = 0; t < 16; ++t) qreg[t] = qrow[t];
    }
    __syncthreads();

    for (int off = oph; off < NOFF; off += 4) {
        int j = i0 + dst + off - WH;
        float s;
        if (j < 0 || j >= S_LEN) {
            s = -INFINITY;
        } else {
            int lr = dst + off;
            const float4* kr = (const float4*)(ks + lr * 68);
            float acc = 0.f;
#pragma unroll
            for (int t = 0; t < 16; ++t) {
                float4 a = qreg[t], bb = kr[t];
                acc += a.x * bb.x + a.y * bb.y + a.z * bb.z + a.w * bb.w;
            }
            s = (am[lr] >= 0.f) ? acc : -1e9f;
        }
        sc[off * 64 + dst] = s;
    }
    __syncthreads();

    if (tid < 64) {
        float mx = -INFINITY;
        for (int o = 0; o < NOFF; ++o) mx = fmaxf(mx, sc[o * 64 + tid]);
        float dn = 0.f;
        for (int o = 0; o < NOFF; ++o) dn += expf(sc[o * 64 + tid] - mx);
        smx[tid] = mx; sidn[tid] = 1.f / dn;
    }
    __syncthreads();

    for (int e = tid; e < 64 * NOFF; e += 256) {
        int d = e / NOFF, off = e - d * NOFF;
        float pv = expf(sc[off * 64 + d] - smx[d]) * sidn[d];
        P[(size_t)(i0 + d) * PROW + h * NOFF + off] = pv;
    }
}

// ---------------------------------------------------------------------------
// diffuse: block = 32 nodes x 128 cols. h-tile (96x128) + P slice in LDS.
// Each thread slides the diagonal: each h float4 read once, used by 4 nodes.
// ---------------------------------------------------------------------------
#define DN 32
#define DC 128
__global__ __launch_bounds__(256)
void diffuse(const float* __restrict__ hin, const float* __restrict__ v,
             const float* __restrict__ P, float* __restrict__ hout,
             unsigned short* __restrict__ hb)
{
    const int i0 = blockIdx.x * DN;
    const int c0 = blockIdx.y * DC;
    const int h0 = c0 >> 6;
    const int tid = threadIdx.x;
    __shared__ float hs[96 * DC];       // rows j = i0-32+lr
    __shared__ float ps[DN * 130];      // [n][hh][off], hh in {0,1}

    for (int e = tid; e < 96 * (DC / 4); e += 256) {
        int lr = e >> 5, c4 = e & 31;
        int j = i0 - WH + lr;
        int jc = min(max(j, 0), S_LEN - 1);
        *(float4*)(hs + lr * DC + c4 * 4) =
            *(const float4*)(hin + (size_t)jc * E_DIM + c0 + c4 * 4);
    }
    for (int e = tid; e < DN * 130; e += 256) {
        int n = e / 130, r = e - n * 130;
        ps[e] = P[(size_t)(i0 + n) * PROW + h0 * NOFF + r];
    }
    __syncthreads();

    const int c4 = (tid & 31) * 4;
    const int hh = c4 >> 6;
    const int nb = (tid >> 5) * 4;
    const float4* h4 = (const float4*)hs;
    const int hidx = c4 >> 2;
    const float* pb = ps + hh * NOFF;

    float4 a0 = {0,0,0,0}, a1 = a0, a2 = a0, a3 = a0;
    for (int lr = nb; lr <= nb + 67; ++lr) {
        float4 hval = h4[lr * (DC / 4) + hidx];
        int o0 = lr - nb;
        if ((unsigned)o0 <= 64u) {
            float p = pb[(nb + 0) * 130 + o0];
            a0.x += p * hval.x; a0.y += p * hval.y; a0.z += p * hval.z; a0.w += p * hval.w;
        }
        int o1 = o0 - 1;
        if ((unsigned)o1 <= 64u) {
            float p = pb[(nb + 1) * 130 + o1];
            a1.x += p * hval.x; a1.y += p * hval.y; a1.z += p * hval.z; a1.w += p * hval.w;
        }
        int o2 = o0 - 2;
        if ((unsigned)o2 <= 64u) {
            float p = pb[(nb + 2) * 130 + o2];
            a2.x += p * hval.x; a2.y += p * hval.y; a2.z += p * hval.z; a2.w += p * hval.w;
        }
        int o3 = o0 - 3;
        if ((unsigned)o3 <= 64u) {
            float p = pb[(nb + 3) * 130 + o3];
            a3.x += p * hval.x; a3.y += p * hval.y; a3.z += p * hval.z; a3.w += p * hval.w;
        }
    }

#pragma unroll
    for (int nn = 0; nn < 4; ++nn) {
        float4 a = (nn == 0) ? a0 : (nn == 1) ? a1 : (nn == 2) ? a2 : a3;
        size_t base = (size_t)(i0 + nb + nn) * E_DIM + c0 + c4;
        float4 vv = *(const float4*)(v + base);
        float4 o;
        o.x = 0.9f * a.x + 0.1f * vv.x;
        o.y = 0.9f * a.y + 0.1f * vv.y;
        o.z = 0.9f * a.z + 0.1f * vv.z;
        o.w = 0.9f * a.w + 0.1f * vv.w;
        *(float4*)(hout + base) = o;
        if (hb) {
            ushort4 ob;
            ob.x = f2bf(o.x); ob.y = f2bf(o.y); ob.z = f2bf(o.z); ob.w = f2bf(o.w);
            *(ushort4*)(hb + base) = ob;
        }
    }
}

// ---------------------------------------------------------------------------
__global__ __launch_bounds__(256)
void layernorm(const float* __restrict__ y, const float* __restrict__ g,
               const float* __restrict__ b, float* __restrict__ out)
{
    const int i = blockIdx.x;
    const int tid = threadIdx.x;
    float x0 = y[(size_t)i * E_DIM + tid];
    float x1 = y[(size_t)i * E_DIM + 256 + tid];
    float s = x0 + x1, s2 = x0 * x0 + x1 * x1;
#pragma unroll
    for (int o = 1; o < 64; o <<= 1) {
        s  += __shfl_xor(s, o, 64);
        s2 += __shfl_xor(s2, o, 64);
    }
    __shared__ float ssum[4], ssq[4];
    int wv = tid >> 6, ln = tid & 63;
    if (ln == 0) { ssum[wv] = s; ssq[wv] = s2; }
    __syncthreads();
    float tot  = ssum[0] + ssum[1] + ssum[2] + ssum[3];
    float tot2 = ssq[0] + ssq[1] + ssq[2] + ssq[3];
    float mu = tot * (1.f / 512.f);
    float var = tot2 * (1.f / 512.f) - mu * mu;
    float rs = rsqrtf(var + 1e-12f);
    out[(size_t)i * E_DIM + tid]       = (x0 - mu) * rs * g[tid]       + b[tid];
    out[(size_t)i * E_DIM + 256 + tid] = (x1 - mu) * rs * g[tid + 256] + b[tid + 256];
}

// ---------------------------------------------------------------------------
extern "C" void kernel_launch(void* const* d_in, const int* in_sizes, int n_in,
                              void* d_out, int out_size, void* d_ws, size_t ws_size,
                              hipStream_t stream)
{
    const float* x     = (const float*)d_in[0];
    const float* amask = (const float*)d_in[1];
    const float* Wq = (const float*)d_in[4];
    const float* bq = (const float*)d_in[5];
    const float* Wk = (const float*)d_in[6];
    const float* bk = (const float*)d_in[7];
    const float* Wv = (const float*)d_in[8];
    const float* bv = (const float*)d_in[9];
    const float* Wo = (const float*)d_in[10];
    const float* bo = (const float*)d_in[11];
    const float* lng = (const float*)d_in[12];
    const float* lnb = (const float*)d_in[13];
    float* out = (float*)d_out;

    float* ws = (float*)d_ws;
    float* q = ws;
    float* k = ws + (size_t)NE;
    float* v = ws + (size_t)2 * NE;
    float* P = ws + (size_t)3 * NE;
    unsigned short* xb  = (unsigned short*)(ws + (size_t)3 * NE + PN);
    unsigned short* WqT = xb + (size_t)NE;
    unsigned short* WkT = WqT + E_DIM * E_DIM;
    unsigned short* WvT = WkT + E_DIM * E_DIM;
    unsigned short* WoT = WvT + E_DIM * E_DIM;
    unsigned short* hb = xb;   // reuse: xb dead after qkv_gemm
    float* hA = k;             // reuse: k dead after scores
    float* hB = q;             // reuse: q dead after scores
    float* y  = v;             // reuse: v dead after final diffuse

    prep<<<dim3(8, 8, 5), 256, 0, stream>>>(x, Wq, Wk, Wv, Wo, xb, WqT, WkT, WvT, WoT);

    qkv_gemm<<<dim3(8, 32, 3), 256, 0, stream>>>(xb, WqT, bq, WkT, bk, WvT, bv, q, k, v);

    scores_kernel<<<dim3(32, 8), 256, 0, stream>>>(q, k, amask, P);

    diffuse<<<dim3(64, 4), 256, 0, stream>>>(v,  v, P, hA, nullptr);
    diffuse<<<dim3(64, 4), 256, 0, stream>>>(hA, v, P, hB, nullptr);
    diffuse<<<dim3(64, 4), 256, 0, stream>>>(hB, v, P, hA, nullptr);
    diffuse<<<dim3(64, 4), 256, 0, stream>>>(hA, v, P, hB, nullptr);
    diffuse<<<dim3(64, 4), 256, 0, stream>>>(hB, v, P, hA, hb);

    o_gemm<<<dim3(8, 32), 256, 0, stream>>>(hb, WoT, bo, x, y);

    layernorm<<<S_LEN, 256, 0, stream>>>(y, lng, lnb, out);
}

// Round 3
// 193.905 us; speedup vs baseline: 1.4467x; 1.2049x over previous
//
#include <hip/hip_runtime.h>
#include <math.h>

#define S_LEN 2048
#define E_DIM 512
#define NE (S_LEN * E_DIM)
#define H_NUM 8
#define WH 32
#define NOFF 65
#define PROW (H_NUM * NOFF) /* 520 */
#define PN (S_LEN * PROW)

typedef float f32x4 __attribute__((ext_vector_type(4)));
typedef short short8 __attribute__((ext_vector_type(8)));

__device__ __forceinline__ unsigned short f2bf(float f) {
    union { float f; unsigned u; } cv; cv.f = f;
    unsigned u = cv.u;
    u += 0x7fffu + ((u >> 16) & 1u);   // RNE
    return (unsigned short)(u >> 16);
}
__device__ __forceinline__ unsigned pk2(float x, float y) {
    return (unsigned)f2bf(x) | ((unsigned)f2bf(y) << 16);
}

// ---------------------------------------------------------------------------
// qkv: C = (x@W + bias)*scale from fp32 x and fp32 W (row-major [k][n]).
// In-kernel cast to bf16; B staged via column-gather (coalesced along n),
// stored transposed [n][k] in LDS. Tile 64x64, 4 waves, 2x2 MFMA 16x16x32.
// ---------------------------------------------------------------------------
__device__ __forceinline__ void mfma_gemm_f32(
    const float* __restrict__ A, const float* __restrict__ W,
    const float* __restrict__ bias, float* __restrict__ C,
    float scale, int m0, int n0)
{
    __shared__ unsigned short As[64 * 40];  // [m][k] pad 40
    __shared__ unsigned short Bs[64 * 40];  // [n][k] pad 40
    const int tid = threadIdx.x;
    const int lane = tid & 63, wave = tid >> 6;
    const int quad = lane >> 4, l16 = lane & 15;
    const int wr = (wave >> 1) * 32, wc = (wave & 1) * 32;
    const int ar = tid >> 2, ac = (tid & 3) * 8;      // A: row, k-chunk
    const int bn = tid & 63, bk0 = (tid >> 6) * 8;    // B: n-col, k-group

    f32x4 acc00 = {0.f,0.f,0.f,0.f}, acc01 = acc00, acc10 = acc00, acc11 = acc00;

    for (int kk = 0; kk < E_DIM; kk += 32) {
        float4 a0 = *(const float4*)(A + (size_t)(m0 + ar) * E_DIM + kk + ac);
        float4 a1 = *(const float4*)(A + (size_t)(m0 + ar) * E_DIM + kk + ac + 4);
        float b[8];
#pragma unroll
        for (int j = 0; j < 8; ++j)
            b[j] = W[(size_t)(kk + bk0 + j) * E_DIM + n0 + bn];
        __syncthreads();   // previous iter's fragment reads done
        uint4 ap; ap.x = pk2(a0.x, a0.y); ap.y = pk2(a0.z, a0.w);
        ap.z = pk2(a1.x, a1.y); ap.w = pk2(a1.z, a1.w);
        *(uint4*)(As + ar * 40 + ac) = ap;
        uint4 bp; bp.x = pk2(b[0], b[1]); bp.y = pk2(b[2], b[3]);
        bp.z = pk2(b[4], b[5]); bp.w = pk2(b[6], b[7]);
        *(uint4*)(Bs + bn * 40 + bk0) = bp;
        __syncthreads();
        short8 fa0 = *(const short8*)(As + (wr + l16) * 40 + quad * 8);
        short8 fa1 = *(const short8*)(As + (wr + 16 + l16) * 40 + quad * 8);
        short8 fb0 = *(const short8*)(Bs + (wc + l16) * 40 + quad * 8);
        short8 fb1 = *(const short8*)(Bs + (wc + 16 + l16) * 40 + quad * 8);
        acc00 = __builtin_amdgcn_mfma_f32_16x16x32_bf16(fa0, fb0, acc00, 0, 0, 0);
        acc01 = __builtin_amdgcn_mfma_f32_16x16x32_bf16(fa0, fb1, acc01, 0, 0, 0);
        acc10 = __builtin_amdgcn_mfma_f32_16x16x32_bf16(fa1, fb0, acc10, 0, 0, 0);
        acc11 = __builtin_amdgcn_mfma_f32_16x16x32_bf16(fa1, fb1, acc11, 0, 0, 0);
    }

    // C/D layout: col = lane&15, row = quad*4 + reg
#pragma unroll
    for (int mi = 0; mi < 2; ++mi) {
#pragma unroll
        for (int ni = 0; ni < 2; ++ni) {
            f32x4 a = (mi == 0) ? ((ni == 0) ? acc00 : acc01)
                                : ((ni == 0) ? acc10 : acc11);
            int n = n0 + wc + ni * 16 + l16;
            float bval = bias[n];
#pragma unroll
            for (int r = 0; r < 4; ++r) {
                int m = m0 + wr + mi * 16 + quad * 4 + r;
                C[(size_t)m * E_DIM + n] = (a[r] + bval) * scale;
            }
        }
    }
}

__global__ __launch_bounds__(256)
void qkv_gemm(const float* __restrict__ x,
              const float* __restrict__ Wq, const float* __restrict__ bq,
              const float* __restrict__ Wk, const float* __restrict__ bk,
              const float* __restrict__ Wv, const float* __restrict__ bv,
              float* __restrict__ q, float* __restrict__ k, float* __restrict__ v)
{
    const float* W; const float* b; float* o; float sc;
    if (blockIdx.z == 0)      { W = Wq; b = bq; o = q; sc = 0.125f; }
    else if (blockIdx.z == 1) { W = Wk; b = bk; o = k; sc = 1.0f; }
    else                      { W = Wv; b = bv; o = v; sc = 1.0f; }
    mfma_gemm_f32(x, W, b, o, sc, blockIdx.y * 64, blockIdx.x * 64);
}

// ---------------------------------------------------------------------------
// scores: block = 32 dst x 1 head (512 blocks). P has exact zeros off-band.
// ---------------------------------------------------------------------------
#define SDN 32
__global__ __launch_bounds__(256)
void scores_kernel(const float* __restrict__ q, const float* __restrict__ k,
                   const float* __restrict__ amask, float* __restrict__ P)
{
    const int i0 = blockIdx.x * SDN;
    const int h  = blockIdx.y;
    const int tid = threadIdx.x;
    __shared__ float ks[96 * 68];
    __shared__ float am[96];
    __shared__ float sc[SDN * 66];     // [dst][off]
    __shared__ float smx[SDN], sidn[SDN];

    for (int e = tid; e < 96 * 16; e += 256) {
        int lr = e >> 4, c4 = e & 15;
        int j = i0 - WH + lr;
        int jc = min(max(j, 0), S_LEN - 1);
        *(float4*)(ks + lr * 68 + c4 * 4) =
            *(const float4*)(k + (size_t)jc * E_DIM + h * 64 + c4 * 4);
    }
    if (tid < 96) {
        int j = i0 - WH + tid;
        am[tid] = (j >= 0 && j < S_LEN) ? amask[j] : -1.0f;
    }

    const int dst = tid >> 3;          // 32 dst
    const int og  = tid & 7;           // 8 off-groups
    float4 qreg[16];
    {
        const float4* qrow = (const float4*)(q + (size_t)(i0 + dst) * E_DIM + h * 64);
#pragma unroll
        for (int t = 0; t < 16; ++t) qreg[t] = qrow[t];
    }
    __syncthreads();

    for (int off = og; off < NOFF; off += 8) {
        int j = i0 + dst + off - WH;
        float s;
        if (j < 0 || j >= S_LEN) {
            s = -INFINITY;
        } else {
            int lr = dst + off;
            const float4* kr = (const float4*)(ks + lr * 68);
            float acc = 0.f;
#pragma unroll
            for (int t = 0; t < 16; ++t) {
                float4 a = qreg[t], bb = kr[t];
                acc += a.x * bb.x + a.y * bb.y + a.z * bb.z + a.w * bb.w;
            }
            s = (am[lr] >= 0.f) ? acc : -1e9f;
        }
        sc[dst * 66 + off] = s;
    }
    __syncthreads();

    if (tid < SDN) {
        float mx = -INFINITY;
        for (int o = 0; o < NOFF; ++o) mx = fmaxf(mx, sc[tid * 66 + o]);
        float dn = 0.f;
        for (int o = 0; o < NOFF; ++o) dn += expf(sc[tid * 66 + o] - mx);
        smx[tid] = mx; sidn[tid] = 1.f / dn;
    }
    __syncthreads();

    for (int e = tid; e < SDN * NOFF; e += 256) {
        int d = e / NOFF, off = e - d * NOFF;
        float pv = expf(sc[d * 66 + off] - smx[d]) * sidn[d];
        P[(size_t)(i0 + d) * PROW + h * NOFF + off] = pv;
    }
}

// ---------------------------------------------------------------------------
// diffuse2: TWO diffusion steps in one dispatch via halo recompute.
// block = 64 out-nodes x 64 cols (head). in rows 192, mid rows 128 (in LDS).
// Off-band P == 0 exactly, so garbage in clamped halo rows contributes 0.
// ---------------------------------------------------------------------------
__global__ __launch_bounds__(512)
void diffuse2(const float* __restrict__ hin, const float* __restrict__ v,
              const float* __restrict__ P, float* __restrict__ hout)
{
    const int i0 = blockIdx.x * 64;
    const int h  = blockIdx.y;
    const int tid = threadIdx.x;
    __shared__ float hs[192 * 64];     // in rows  [i0-64, i0+128)
    __shared__ float h1[128 * 64];     // mid rows [i0-32, i0+96)
    __shared__ float ps[128 * NOFF];   // P for mid rows

    for (int e = tid; e < 192 * 16; e += 512) {
        int lr = e >> 4, c4 = e & 15;
        int j = i0 - 64 + lr;
        int jc = min(max(j, 0), S_LEN - 1);
        *(float4*)(hs + lr * 64 + c4 * 4) =
            *(const float4*)(hin + (size_t)jc * E_DIM + h * 64 + c4 * 4);
    }
    for (int e = tid; e < 128 * NOFF; e += 512) {
        int mr = e / NOFF, o = e - mr * NOFF;
        int j = i0 - 32 + mr;
        int jc = min(max(j, 0), S_LEN - 1);
        ps[e] = P[(size_t)jc * PROW + h * NOFF + o];
    }
    __syncthreads();

    const int c4 = (tid & 15) * 4;
    const int g  = tid >> 4;           // 32 groups x 4 mid-rows
    const float4* h4 = (const float4*)hs;
    const int ci = tid & 15;

    // ---- step A: mid rows g*4 .. g*4+3 ----
    {
        float4 a0 = {0,0,0,0}, a1 = a0, a2 = a0, a3 = a0;
        const int mb = g * 4;
        for (int lr = mb; lr < mb + 68; ++lr) {
            float4 hval = h4[lr * 16 + ci];
            int o0 = lr - mb;
            if ((unsigned)o0 <= 64u) {
                float p = ps[(mb + 0) * NOFF + o0];
                a0.x += p * hval.x; a0.y += p * hval.y; a0.z += p * hval.z; a0.w += p * hval.w;
            }
            int o1 = o0 - 1;
            if ((unsigned)o1 <= 64u) {
                float p = ps[(mb + 1) * NOFF + o1];
                a1.x += p * hval.x; a1.y += p * hval.y; a1.z += p * hval.z; a1.w += p * hval.w;
            }
            int o2 = o0 - 2;
            if ((unsigned)o2 <= 64u) {
                float p = ps[(mb + 2) * NOFF + o2];
                a2.x += p * hval.x; a2.y += p * hval.y; a2.z += p * hval.z; a2.w += p * hval.w;
            }
            int o3 = o0 - 3;
            if ((unsigned)o3 <= 64u) {
                float p = ps[(mb + 3) * NOFF + o3];
                a3.x += p * hval.x; a3.y += p * hval.y; a3.z += p * hval.z; a3.w += p * hval.w;
            }
        }
#pragma unroll
        for (int r = 0; r < 4; ++r) {
            float4 a = (r == 0) ? a0 : (r == 1) ? a1 : (r == 2) ? a2 : a3;
            int j = i0 - 32 + mb + r;
            int jc = min(max(j, 0), S_LEN - 1);
            float4 vv = *(const float4*)(v + (size_t)jc * E_DIM + h * 64 + c4);
            float4 o;
            o.x = 0.9f * a.x + 0.1f * vv.x;
            o.y = 0.9f * a.y + 0.1f * vv.y;
            o.z = 0.9f * a.z + 0.1f * vv.z;
            o.w = 0.9f * a.w + 0.1f * vv.w;
            *(float4*)(h1 + (mb + r) * 64 + c4) = o;
        }
    }
    __syncthreads();

    // ---- step B: out rows g2*2 .. g2*2+1 ----
    {
        const int g2 = tid >> 4;       // 32 groups x 2 out-rows
        const int ob = g2 * 2;
        const float4* m4 = (const float4*)h1;
        float4 a0 = {0,0,0,0}, a1 = a0;
        for (int lr = ob; lr < ob + 66; ++lr) {
            float4 hval = m4[lr * 16 + ci];
            int o0 = lr - ob;
            if ((unsigned)o0 <= 64u) {
                float p = ps[(ob + 32) * NOFF + o0];
                a0.x += p * hval.x; a0.y += p * hval.y; a0.z += p * hval.z; a0.w += p * hval.w;
            }
            int o1 = o0 - 1;
            if ((unsigned)o1 <= 64u) {
                float p = ps[(ob + 33) * NOFF + o1];
                a1.x += p * hval.x; a1.y += p * hval.y; a1.z += p * hval.z; a1.w += p * hval.w;
            }
        }
#pragma unroll
        for (int r = 0; r < 2; ++r) {
            float4 a = (r == 0) ? a0 : a1;
            size_t base = (size_t)(i0 + ob + r) * E_DIM + h * 64 + c4;
            float4 vv = *(const float4*)(v + base);
            float4 o;
            o.x = 0.9f * a.x + 0.1f * vv.x;
            o.y = 0.9f * a.y + 0.1f * vv.y;
            o.z = 0.9f * a.z + 0.1f * vv.z;
            o.w = 0.9f * a.w + 0.1f * vv.w;
            *(float4*)(hout + base) = o;
        }
    }
}

// ---------------------------------------------------------------------------
// diffuse1: one step. block = 32 nodes x 64 cols (head). 512 blocks.
// ---------------------------------------------------------------------------
__global__ __launch_bounds__(256)
void diffuse1(const float* __restrict__ hin, const float* __restrict__ v,
              const float* __restrict__ P, float* __restrict__ hout)
{
    const int i0 = blockIdx.x * 32;
    const int h  = blockIdx.y;
    const int tid = threadIdx.x;
    __shared__ float hs[96 * 64];
    __shared__ float ps[32 * NOFF];

    for (int e = tid; e < 96 * 16; e += 256) {
        int lr = e >> 4, c4 = e & 15;
        int j = i0 - WH + lr;
        int jc = min(max(j, 0), S_LEN - 1);
        *(float4*)(hs + lr * 64 + c4 * 4) =
            *(const float4*)(hin + (size_t)jc * E_DIM + h * 64 + c4 * 4);
    }
    for (int e = tid; e < 32 * NOFF; e += 256) {
        int mr = e / NOFF, o = e - mr * NOFF;
        ps[e] = P[(size_t)(i0 + mr) * PROW + h * NOFF + o];
    }
    __syncthreads();

    const int c4 = (tid & 15) * 4;
    const int ci = tid & 15;
    const int g  = tid >> 4;           // 16 groups x 2 out-rows
    const int ob = g * 2;
    const float4* h4 = (const float4*)hs;

    float4 a0 = {0,0,0,0}, a1 = a0;
    for (int lr = ob; lr < ob + 66; ++lr) {
        float4 hval = h4[lr * 16 + ci];
        int o0 = lr - ob;
        if ((unsigned)o0 <= 64u) {
            float p = ps[(ob + 0) * NOFF + o0];
            a0.x += p * hval.x; a0.y += p * hval.y; a0.z += p * hval.z; a0.w += p * hval.w;
        }
        int o1 = o0 - 1;
        if ((unsigned)o1 <= 64u) {
            float p = ps[(ob + 1) * NOFF + o1];
            a1.x += p * hval.x; a1.y += p * hval.y; a1.z += p * hval.z; a1.w += p * hval.w;
        }
    }
#pragma unroll
    for (int r = 0; r < 2; ++r) {
        float4 a = (r == 0) ? a0 : a1;
        size_t base = (size_t)(i0 + ob + r) * E_DIM + h * 64 + c4;
        float4 vv = *(const float4*)(v + base);
        float4 o;
        o.x = 0.9f * a.x + 0.1f * vv.x;
        o.y = 0.9f * a.y + 0.1f * vv.y;
        o.z = 0.9f * a.z + 0.1f * vv.z;
        o.w = 0.9f * a.w + 0.1f * vv.w;
        *(float4*)(hout + base) = o;
    }
}

// ---------------------------------------------------------------------------
// oln: y = h@Wo + bo + x, then LayerNorm, fused. Block = 64 rows x 512 cols,
// 512 threads (8 waves: wave w -> Mtile w&3, N-half w>>2). 32 blocks.
// ---------------------------------------------------------------------------
__global__ __launch_bounds__(512)
void oln(const float* __restrict__ hA, const float* __restrict__ Wo,
         const float* __restrict__ bo, const float* __restrict__ x,
         const float* __restrict__ g, const float* __restrict__ lb,
         float* __restrict__ out)
{
    __shared__ unsigned short As[64 * 40];
    __shared__ unsigned short Bs[512 * 40];
    __shared__ float rsum[2][64], rsq[2][64];
    const int tid = threadIdx.x;
    const int lane = tid & 63, wave = tid >> 6;
    const int quad = lane >> 4, l16 = lane & 15;
    const int mtile = wave & 3, nhalf = wave >> 2;
    const int m0 = blockIdx.x * 64;
    const int ar = tid >> 3, ac = (tid & 7) * 4;   // A staging
    const int bn = tid;                            // B staging column

    f32x4 acc[16];
#pragma unroll
    for (int t = 0; t < 16; ++t) acc[t] = (f32x4){0.f,0.f,0.f,0.f};

    for (int kk = 0; kk < E_DIM; kk += 32) {
        float4 av = *(const float4*)(hA + (size_t)(m0 + ar) * E_DIM + kk + ac);
        float bcol[32];
#pragma unroll
        for (int j = 0; j < 32; ++j)
            bcol[j] = Wo[(size_t)(kk + j) * E_DIM + bn];
        __syncthreads();
        uint2 ap; ap.x = pk2(av.x, av.y); ap.y = pk2(av.z, av.w);
        *(uint2*)(As + ar * 40 + ac) = ap;
#pragma unroll
        for (int t = 0; t < 4; ++t) {
            uint4 bp;
            bp.x = pk2(bcol[t*8+0], bcol[t*8+1]); bp.y = pk2(bcol[t*8+2], bcol[t*8+3]);
            bp.z = pk2(bcol[t*8+4], bcol[t*8+5]); bp.w = pk2(bcol[t*8+6], bcol[t*8+7]);
            *(uint4*)(Bs + bn * 40 + t * 8) = bp;
        }
        __syncthreads();
        short8 fa = *(const short8*)(As + (mtile * 16 + l16) * 40 + quad * 8);
#pragma unroll
        for (int nt = 0; nt < 16; ++nt) {
            short8 fb = *(const short8*)(Bs + (nhalf * 256 + nt * 16 + l16) * 40 + quad * 8);
            acc[nt] = __builtin_amdgcn_mfma_f32_16x16x32_bf16(fa, fb, acc[nt], 0, 0, 0);
        }
    }

    // epilogue: bias + resid, then LN stats
    float s[4] = {0.f,0.f,0.f,0.f}, s2[4] = {0.f,0.f,0.f,0.f};
#pragma unroll
    for (int nt = 0; nt < 16; ++nt) {
        int n = nhalf * 256 + nt * 16 + l16;
        float bv = bo[n];
#pragma unroll
        for (int r = 0; r < 4; ++r) {
            int m = m0 + mtile * 16 + quad * 4 + r;
            float vl = acc[nt][r] + bv + x[(size_t)m * E_DIM + n];
            acc[nt][r] = vl;
            s[r] += vl; s2[r] += vl * vl;
        }
    }
#pragma unroll
    for (int o = 1; o < 16; o <<= 1) {
#pragma unroll
        for (int r = 0; r < 4; ++r) {
            s[r]  += __shfl_xor(s[r], o, 64);
            s2[r] += __shfl_xor(s2[r], o, 64);
        }
    }
    if (l16 == 0) {
#pragma unroll
        for (int r = 0; r < 4; ++r) {
            rsum[nhalf][mtile * 16 + quad * 4 + r] = s[r];
            rsq[nhalf][mtile * 16 + quad * 4 + r]  = s2[r];
        }
    }
    __syncthreads();
    float mu[4], rs[4];
#pragma unroll
    for (int r = 0; r < 4; ++r) {
        int rl = mtile * 16 + quad * 4 + r;
        float tot  = rsum[0][rl] + rsum[1][rl];
        float tot2 = rsq[0][rl] + rsq[1][rl];
        float m_ = tot * (1.f / 512.f);
        float var = tot2 * (1.f / 512.f) - m_ * m_;
        mu[r] = m_; rs[r] = rsqrtf(var + 1e-12f);
    }
#pragma unroll
    for (int nt = 0; nt < 16; ++nt) {
        int n = nhalf * 256 + nt * 16 + l16;
        float gv = g[n], bbv = lb[n];
#pragma unroll
        for (int r = 0; r < 4; ++r) {
            int m = m0 + mtile * 16 + quad * 4 + r;
            out[(size_t)m * E_DIM + n] = (acc[nt][r] - mu[r]) * rs[r] * gv + bbv;
        }
    }
}

// ---------------------------------------------------------------------------
extern "C" void kernel_launch(void* const* d_in, const int* in_sizes, int n_in,
                              void* d_out, int out_size, void* d_ws, size_t ws_size,
                              hipStream_t stream)
{
    const float* x     = (const float*)d_in[0];
    const float* amask = (const float*)d_in[1];
    const float* Wq = (const float*)d_in[4];
    const float* bq = (const float*)d_in[5];
    const float* Wk = (const float*)d_in[6];
    const float* bk = (const float*)d_in[7];
    const float* Wv = (const float*)d_in[8];
    const float* bv = (const float*)d_in[9];
    const float* Wo = (const float*)d_in[10];
    const float* bo = (const float*)d_in[11];
    const float* lng = (const float*)d_in[12];
    const float* lnb = (const float*)d_in[13];
    float* out = (float*)d_out;

    float* ws = (float*)d_ws;
    float* q  = ws;
    float* k  = ws + (size_t)NE;
    float* v  = ws + (size_t)2 * NE;
    float* P  = ws + (size_t)3 * NE;
    float* hA = ws + (size_t)3 * NE + PN;
    float* hB = hA + (size_t)NE;

    qkv_gemm<<<dim3(8, 32, 3), 256, 0, stream>>>(x, Wq, bq, Wk, bk, Wv, bv, q, k, v);

    scores_kernel<<<dim3(64, 8), 256, 0, stream>>>(q, k, amask, P);

    diffuse2<<<dim3(32, 8), 512, 0, stream>>>(v,  v, P, hA);   // steps 1-2
    diffuse2<<<dim3(32, 8), 512, 0, stream>>>(hA, v, P, hB);   // steps 3-4
    diffuse1<<<dim3(64, 8), 256, 0, stream>>>(hB, v, P, hA);   // step 5

    oln<<<32, 512, 0, stream>>>(hA, Wo, bo, x, lng, lnb, out);
}